// Round 7
// baseline (24688.458 us; speedup 1.0000x reference)
//
#include <hip/hip_runtime.h>
#include <stdint.h>
#include <stddef.h>

// ---------------------------------------------------------------------------
// Autoregressive decoder for MI355X (gfx950) — multi-launch, 3 kernels/step.
// vs v6 (4 kernels/step, 21.2 ms):
//   1) energy/enc stored fp8-e4m3 (halves s3's 64 MB/step stream); decode via
//      256-entry LDS table.
//   2) mel = co@Wp^T via MFMA with bf16-swizzled Wp (kills the 16 MB/step
//      fp32 Wp re-read).
//   3) k_s4 merged into k_s34: attention WGs bump a completion counter after
//      their ctx atomics drain; 64 co-WGs spin (bounded) then GEMM with ctx
//      via 32-deep SYSTEM-scope (LLC) loads; gh1' WGs ride along spin-free.
// Per step: s1 (GRU0 + mel/gate writers t-1 + ctx/done zero) -> s2 (GRU1 +
// gh0') -> s34 (attention fp8 + co + gh1'). Kernel boundaries = coherence
// for all plain traffic; ctx/den/done go through LLC (atomics + sc loads).
// ---------------------------------------------------------------------------

#define TM 400

typedef unsigned short ushort_t;
typedef unsigned long long u64_t;
typedef short    short8  __attribute__((ext_vector_type(8)));
typedef float    float4v __attribute__((ext_vector_type(4)));
typedef unsigned uint2v  __attribute__((ext_vector_type(2)));

#define DEVI static __device__ __forceinline__

// swizzled-weight segment bases (in shorts, within g_sw)
#define SB_WF   0
#define SB_IH1  3145728
#define SB_HH0  6291456
#define SB_HH1  9437184
#define SB_AT   12582912
#define SB_WC   13631488
#define SB_WP   15728640
#define SW_TOT  15859712

__device__ __align__(16) ushort_t g_sw[SW_TOT];      // bf16 weights (L2-hot)
__device__ __align__(16) float    g_wf[3145728];     // WF = W_ih0 @ Wp (fp32)
__device__ __align__(16) ushort_t g_encb[16777216];  // enc bf16 (prologue GEMM A)
__device__ __align__(16) unsigned char g_en8[16777216]; // energy fp8 e4m3
__device__ __align__(16) unsigned char g_ec8[16777216]; // enc fp8 e4m3
__device__ __align__(16) ushort_t g_h0b[32768], g_h1b[32768];
__device__ __align__(16) float    g_h0f[32768], g_h1f[32768];
__device__ __align__(16) float    g_b0f[3072];
__device__ __align__(16) float    g_gh0[98304], g_gh1[98304];
__device__ __align__(16) float    g_ctxn[32768], g_sden[32];   // LLC atomics
__device__ __align__(16) float    g_cof[32768];      // co fp32
__device__ __align__(16) ushort_t g_cob[32768];      // co bf16
__device__ __align__(64) unsigned g_done[16];        // [0] attn completion ctr

DEVI ushort_t f2b(float f) {                // float -> bf16 bits, RNE
  union { float f; uint32_t u; } c; c.f = f;
  uint32_t u = c.u + 0x7fffu + ((c.u >> 16) & 1u);
  return (ushort_t)(u >> 16);
}
DEVI float sigm(float x) { return 1.f / (1.f + __expf(-x)); }

// float -> fp8 e4m3fn (bias 7, max 448, denormals m*2^-9), RNE-ish.
DEVI unsigned char f2e4m3(float f) {
  union { float f; uint32_t u; } c; c.f = f;
  const unsigned s = (c.u >> 24) & 0x80u;
  const float a = fabsf(f);
  if (a >= 448.f) return (unsigned char)(s | 0x7Eu);
  if (a < 0.015625f) {                       // denormal: round(a * 512)
    int m = (int)(a * 512.f + 0.5f);         // 0..8
    if (m >= 8) return (unsigned char)(s | 0x08u);
    return (unsigned char)(s | (unsigned)m);
  }
  int e32 = (int)((c.u >> 23) & 0xffu);
  uint32_t m3 = (c.u >> 20) & 7u;
  const uint32_t rem = c.u & 0xfffffu;
  if (rem > 0x80000u || (rem == 0x80000u && (m3 & 1u))) {
    if (++m3 == 8u) { m3 = 0u; ++e32; }
  }
  const int e8 = e32 - 120;                  // 1..15 expected
  if (e8 >= 16) return (unsigned char)(s | 0x7Eu);
  return (unsigned char)(s | ((unsigned)e8 << 3) | m3);
}

DEVI float4v mfma16(short8 a, short8 b, float4v c) {
  return __builtin_amdgcn_mfma_f32_16x16x32_bf16(a, b, c, 0, 0, 0);
}

// ---- LLC-coherent helpers (SYSTEM scope -> sc0 sc1, compiler-tracked) -----
DEVI u64_t ld_sc8(const void* p) {
  return __hip_atomic_load((const u64_t*)p, __ATOMIC_RELAXED,
                           __HIP_MEMORY_SCOPE_SYSTEM);
}
DEVI float ld_scf(const float* p) {
  return __hip_atomic_load(p, __ATOMIC_RELAXED, __HIP_MEMORY_SCOPE_SYSTEM);
}

// A: bf16 [32 x 1024] row-major (plain loads); B: pre-swizzled frags. K=1024.
DEVI float4v gemm_plain(const ushort_t* Ab, const ushort_t* Bw,
                        int ntile, int mu, int lane) {
  float4v acc = {0.f, 0.f, 0.f, 0.f};
  const ushort_t* a = Ab + (size_t)(mu * 16 + (lane & 15)) * 1024 + ((lane >> 4) << 3);
  const ushort_t* b = Bw + ((size_t)ntile * 32 * 64 + lane) * 8;
  for (int kb = 0; kb < 32; ++kb) {
    short8 av = *(const short8*)(a + kb * 32);
    acc = mfma16(av, *(const short8*)(b + (size_t)kb * 512), acc);
  }
  return acc;
}

// co gemm (merged kernel): K=2048, A = [h1 bf16 plain | ctx*inv via sc loads]
DEVI float4v gemm_scE2(const ushort_t* h1b, const float* ctxn, const float* sden,
                       const ushort_t* Bw, int ntile, int mu, int lane) {
  float4v acc = {0.f, 0.f, 0.f, 0.f};
  const int m = mu * 16 + (lane & 15), ko = (lane >> 4) << 3;
  const ushort_t* a0 = h1b + (size_t)m * 1024 + ko;
  const float* a1 = ctxn + (size_t)m * 1024 + ko;
  const float den = ld_scf(&sden[m]);
  const float inv = (den > 1e-35f) ? (1.f / den) : 0.f;
  const ushort_t* b = Bw + ((size_t)ntile * 64 * 64 + lane) * 8;
  for (int kb = 0; kb < 32; ++kb)
    acc = mfma16(*(const short8*)(a0 + kb * 32),
                 *(const short8*)(b + (size_t)kb * 512), acc);
  for (int c = 0; c < 4; ++c) {          // 8 kbs/chunk, 32 sc loads in flight
    u64_t t[32];
#pragma unroll
    for (int j = 0; j < 8; ++j)
#pragma unroll
      for (int q = 0; q < 4; ++q)
        t[j * 4 + q] = ld_sc8(a1 + (c * 8 + j) * 32 + q * 2);
#pragma unroll
    for (int j = 0; j < 8; ++j) {
      short8 av;
#pragma unroll
      for (int q = 0; q < 4; ++q) {
        union { u64_t u; float f[2]; } w; w.u = t[j * 4 + q];
        av[q * 2]     = (short)f2b(w.f[0] * inv);
        av[q * 2 + 1] = (short)f2b(w.f[1] * inv);
      }
      acc = mfma16(av, *(const short8*)(b + (size_t)(32 + c * 8 + j) * 512), acc);
    }
  }
  return acc;
}

// scatter C-fragment into LDS: sh[q*256 + m*16 + n]
DEVI void put_tile(float* sh, int q, int lane, float4v a) {
  const int base = q * 256 + (lane & 15);
#pragma unroll
  for (int i = 0; i < 4; ++i) sh[base + ((lane >> 4) * 4 + i) * 16] = a[i];
}

// ---------------------------------------------------------------------------
// Prologue: WF = W_ih0 @ Wp  (fp32, [3072 x 1024])
// ---------------------------------------------------------------------------
__global__ void k_wf(const float* __restrict__ Wih0, const float* __restrict__ Wp) {
  __shared__ __align__(16) float As[32][128];
  __shared__ __align__(16) float Bs[128][64];
  const int tid = threadIdx.x;
  const int nt = blockIdx.x >> 4, kt = blockIdx.x & 15;
  const int n0 = nt * 32, k0 = kt * 64;
  {
    const int r = tid >> 3, c0 = (tid & 7) * 16;
    for (int i = 0; i < 16; i += 4)
      *(float4v*)&As[r][c0 + i] = *(const float4v*)&Wih0[(size_t)(n0 + r) * 128 + c0 + i];
  }
  {
    const int r = tid >> 1, c0 = (tid & 1) * 32;
    for (int i = 0; i < 32; i += 4)
      *(float4v*)&Bs[r][c0 + i] = *(const float4v*)&Wp[(size_t)r * 1024 + k0 + c0 + i];
  }
  __syncthreads();
  const int rn = tid >> 3, kq = (tid & 7) * 8;
  float acc[8] = {0.f, 0.f, 0.f, 0.f, 0.f, 0.f, 0.f, 0.f};
  for (int m = 0; m < 128; ++m) {
    const float a = As[rn][m];
#pragma unroll
    for (int j = 0; j < 8; ++j) acc[j] += a * Bs[m][kq + j];
  }
  float* dst = g_wf + (size_t)(n0 + rn) * 1024 + k0 + kq;
#pragma unroll
  for (int j = 0; j < 8; ++j) dst[j] = acc[j];
}

// Prologue: enc fp32 -> bf16 (for the energy GEMM's A operand).
__global__ void k_encb(const float* __restrict__ enc) {
  const size_t i = ((size_t)blockIdx.x * 256 + threadIdx.x) * 8;
  if (i >= 16777216) return;
  float4v a = *(const float4v*)(enc + i);
  float4v b = *(const float4v*)(enc + i + 4);
  short8 r;
#pragma unroll
  for (int j = 0; j < 4; ++j) { r[j] = (short)f2b(a[j]); r[4 + j] = (short)f2b(b[j]); }
  *(short8*)(g_encb + i) = r;
}

// Prologue: enc fp32 -> fp8 e4m3 (for phase-D ctx accumulation).
__global__ void k_q8(const float* __restrict__ enc) {
  const size_t i = ((size_t)blockIdx.x * 256 + threadIdx.x) * 8;
  if (i >= 16777216) return;
  float4v a = *(const float4v*)(enc + i);
  float4v b = *(const float4v*)(enc + i + 4);
  unsigned lo = 0, hi = 0;
#pragma unroll
  for (int j = 0; j < 4; ++j) {
    lo |= (unsigned)f2e4m3(a[j]) << (8 * j);
    hi |= (unsigned)f2e4m3(b[j]) << (8 * j);
  }
  uint2v o; o[0] = lo; o[1] = hi;
  *(uint2v*)(g_ec8 + i) = o;
}

// ---------------------------------------------------------------------------
// Prologue: round fp32 weights to bf16 and repack into B-fragment order.
// lane L holds B[k = kb*32 + (L>>4)*8 + i][n = ntile*16 + (L&15)]
// ---------------------------------------------------------------------------
__global__ void k_swz(const float* __restrict__ W1, const float* __restrict__ W2,
                      const float* __restrict__ W3, const float* __restrict__ WA,
                      const float* __restrict__ WC, const float* __restrict__ Wp) {
  long fid = (long)blockIdx.x * 256 + threadIdx.x;
  if (fid >= 1982464) return;
  const float* src; int N, K; long base, local;
  if      (fid < 393216)  { src = g_wf; N = 3072; K = 1024; base = SB_WF;  local = fid; }
  else if (fid < 786432)  { src = W1;   N = 3072; K = 1024; base = SB_IH1; local = fid - 393216; }
  else if (fid < 1179648) { src = W2;   N = 3072; K = 1024; base = SB_HH0; local = fid - 786432; }
  else if (fid < 1572864) { src = W3;   N = 3072; K = 1024; base = SB_HH1; local = fid - 1179648; }
  else if (fid < 1703936) { src = WA;   N = 1024; K = 1024; base = SB_AT;  local = fid - 1572864; }
  else if (fid < 1966080) { src = WC;   N = 1024; K = 2048; base = SB_WC;  local = fid - 1703936; }
  else                    { src = Wp;   N = 128;  K = 1024; base = SB_WP;  local = fid - 1966080; }
  const int L = (int)(local & 63);
  long rest = local >> 6;
  const int KB = K >> 5;
  const int kb = (int)(rest % KB);
  const int nt = (int)(rest / KB);
  const int n  = nt * 16 + (L & 15);
  const int k0 = kb * 32 + ((L >> 4) << 3);
  short8 r;
#pragma unroll
  for (int i = 0; i < 8; ++i)
    r[i] = (short)f2b(src[(size_t)n * K + (k0 + i)]);
  *(short8*)(g_sw + base + local * 8) = r;
}

// ---------------------------------------------------------------------------
// Prologue: energy = enc @ W_attn^T + b_attn -> fp8 e4m3 [32][512][1024].
// ---------------------------------------------------------------------------
__global__ void k_energy(const float* __restrict__ b_attn) {
  __shared__ __align__(16) float sh[2048];
  const int tid = threadIdx.x, lane = tid & 63, wv = tid >> 6;
  const int rt = blockIdx.x;
  const ushort_t* Ab = g_encb + (size_t)rt * 32 * 1024;
  float* shw = sh + wv * 512;
  for (int i = 0; i < 16; ++i) {
    const int nt = wv * 16 + i;
    put_tile(shw, 0, lane, gemm_plain(Ab, g_sw + SB_AT, nt, 0, lane));
    put_tile(shw, 1, lane, gemm_plain(Ab, g_sw + SB_AT, nt, 1, lane));
    __syncthreads();
    const int row = lane >> 1, cf = (lane & 1) * 8;
    const int q = row >> 4, r = row & 15;
    unsigned lo = 0, hi = 0;
#pragma unroll
    for (int j = 0; j < 4; ++j) {
      lo |= (unsigned)f2e4m3(shw[q * 256 + r * 16 + cf + j] + b_attn[nt * 16 + cf + j]) << (8 * j);
      hi |= (unsigned)f2e4m3(shw[q * 256 + r * 16 + cf + 4 + j] + b_attn[nt * 16 + cf + 4 + j]) << (8 * j);
    }
    uint2v o; o[0] = lo; o[1] = hi;
    *(uint2v*)(g_en8 + (size_t)(rt * 32 + row) * 1024 + nt * 16 + cf) = o;
    __syncthreads();
  }
}

// Prologue: init states, mask output, fused bias b0f, done ctr.
__global__ void k_init(const float* __restrict__ ehid, const int* __restrict__ lens,
                       const float* __restrict__ Wih0, const float* __restrict__ bp,
                       const float* __restrict__ bih0,
                       float* __restrict__ out, int out_size) {
  int i = blockIdx.x * 256 + threadIdx.x;
  if (i == 0) g_done[0] = 0u;
  if (i < 32768) { float v = ehid[i]; g_h0f[i] = v; g_h0b[i] = f2b(v); }
  else if (i < 65536) {
    int j = i - 32768; float v = ehid[32768 + j];
    g_h1f[j] = v; g_h1b[j] = f2b(v);
  } else if (i < 78336) {
    int mi = i - 65536; int b = mi / 400, tt = mi % 400;
    int idx = 1651200 + mi;
    if (idx < out_size) out[idx] = (tt > lens[b]) ? 1.0f : 0.0f;
  } else if (i < 81408) {
    int n = i - 78336;
    float s = bih0[n];
    const float* wr = Wih0 + (size_t)n * 128;
    for (int m = 0; m < 128; ++m) s += bp[m] * wr[m];
    g_b0f[n] = s;
  }
}

// Prologue: gh0/gh1 for step 0 (h_init @ W_hh^T + b_hh).
__global__ void k_pre(const float* __restrict__ b_hh0, const float* __restrict__ b_hh1) {
  const int wg = blockIdx.x, tid = threadIdx.x;
  const int lane = tid & 63, wv = tid >> 6;
  __shared__ __align__(16) float sh[1536];
  const int qa = (wv < 2) ? wv * 2 : wv + 2;
  const int qb = (wv < 2) ? wv * 2 + 1 : -1;
  const ushort_t* Ab = (wg < 64) ? g_h0b : g_h1b;
  const ushort_t* Bw = g_sw + ((wg < 64) ? SB_HH0 : SB_HH1);
  const float* bhh = (wg < 64) ? b_hh0 : b_hh1;
  float* ghb = (wg < 64) ? g_gh0 : g_gh1;
  const int w16 = wg & 63;
  { int g = qa >> 1, mu = qa & 1;
    put_tile(sh, qa, lane, gemm_plain(Ab, Bw, g * 64 + w16, mu, lane)); }
  if (qb >= 0) { int g = qb >> 1, mu = qb & 1;
    put_tile(sh, qb, lane, gemm_plain(Ab, Bw, g * 64 + w16, mu, lane)); }
  __syncthreads();
  const int jl = tid & 15, mr = tid >> 4, jg = w16 * 16 + jl;
#pragma unroll
  for (int mu = 0; mu < 2; ++mu) {
    const int b = mu * 16 + mr;
#pragma unroll
    for (int g = 0; g < 3; ++g)
      ghb[b * 3072 + g * 1024 + jg] = sh[(g * 2 + mu) * 256 + tid] + bhh[g * 1024 + jg];
  }
}

// ---------------------------------------------------------------------------
// s1: GRU0 (WGs 0..63); mel MFMA writers t-1 (64..71); gate writer (72);
// zero ctx/den/done (73..80). Grid 81.
// ---------------------------------------------------------------------------
__global__ void k_s1(int t, const float* __restrict__ b_ih0, const float* __restrict__ bp,
                     const float* __restrict__ Wg, const float* __restrict__ bg,
                     const int* __restrict__ lens,
                     float* __restrict__ out, int out_size) {
  const int wg = blockIdx.x, tid = threadIdx.x;
  const int lane = tid & 63, wv = tid >> 6;
  __shared__ __align__(16) float sh[1536];
  if (wg < 64) {
    if (t >= TM) return;
    const int qa = (wv < 2) ? wv * 2 : wv + 2;
    const int qb = (wv < 2) ? wv * 2 + 1 : -1;
    const ushort_t* SW = g_sw + SB_WF;
    float4v acc;
    { int g = qa >> 1, mu = qa & 1;
      acc = (t > 0) ? gemm_plain(g_cob, SW, g * 64 + wg, mu, lane)
                    : float4v{0.f, 0.f, 0.f, 0.f};
      put_tile(sh, qa, lane, acc); }
    if (qb >= 0) { int g = qb >> 1, mu = qb & 1;
      acc = (t > 0) ? gemm_plain(g_cob, SW, g * 64 + wg, mu, lane)
                    : float4v{0.f, 0.f, 0.f, 0.f};
      put_tile(sh, qb, lane, acc); }
    __syncthreads();
    const int jl = tid & 15, mr = tid >> 4, jg = wg * 16 + jl;
    const float* bs = (t > 0) ? g_b0f : b_ih0;   // t=0: dec_in = 0 -> plain b_ih0
    const float bir = bs[jg], biz = bs[1024 + jg], bin = bs[2048 + jg];
#pragma unroll
    for (int mu = 0; mu < 2; ++mu) {
      const int b = mu * 16 + mr;
      float gr = sh[mu * 256 + tid]       + bir + g_gh0[b * 3072 + jg];
      float gz = sh[(2 + mu) * 256 + tid] + biz + g_gh0[b * 3072 + 1024 + jg];
      float gn = sh[(4 + mu) * 256 + tid] + bin;
      float r = sigm(gr), z = sigm(gz);
      float nn = tanhf(gn + r * g_gh0[b * 3072 + 2048 + jg]);
      float h = (1.f - z) * nn + z * g_h0f[b * 1024 + jg];
      g_h0f[b * 1024 + jg] = h; g_h0b[b * 1024 + jg] = f2b(h);
    }
  } else if (wg < 72) {
    if (t == 0) return;
    const int nt = wg - 64;
    if (wv < 2)
      put_tile(sh, wv, lane, gemm_plain(g_cob, g_sw + SB_WP, nt, wv, lane));
    __syncthreads();
    const int jl = tid & 15, mr = tid >> 4;
    const int m = nt * 16 + jl;
    const float bpv = bp[m];
#pragma unroll
    for (int mu = 0; mu < 2; ++mu) {
      const int b = mu * 16 + mr;
      const bool mk = (t - 1) > lens[b];
      const float v = mk ? 0.f : (sh[mu * 256 + tid] + bpv);
      const int oidx = b * 51200 + (t - 1) * 128 + m;
      if (oidx < out_size) out[oidx] = v;
    }
  } else if (wg == 72) {
    if (t == 0) return;
    const int b = tid >> 3, seg = tid & 7;
    const float* cop = g_cof + b * 1024 + seg * 128;
    const float* wgp = Wg + seg * 128;
    float s = 0.f;
#pragma unroll 8
    for (int k = 0; k < 128; k += 4) {
      float4v cv = *(const float4v*)(cop + k);
      float4v wv4 = *(const float4v*)(wgp + k);
      s += cv[0] * wv4[0] + cv[1] * wv4[1] + cv[2] * wv4[2] + cv[3] * wv4[3];
    }
    for (int o = 1; o < 8; o <<= 1) s += __shfl_xor(s, o, 64);
    if (seg == 0) {
      const bool mk = (t - 1) > lens[b];
      const float g = mk ? 1000.f : (s + bg[0]);
      const int oidx = 1638400 + b * 400 + (t - 1);
      if (oidx < out_size) out[oidx] = g;
    }
  } else {                      // wg 73..80: zero ctx/den/done for this step
    const int z0 = (wg - 73) * 256 + tid;
#pragma unroll
    for (int r4 = 0; r4 < 16; ++r4) g_ctxn[z0 + r4 * 2048] = 0.f;
    if (wg == 73 && tid < 32) g_sden[tid] = 0.f;
    if (wg == 73 && tid == 0)
      __hip_atomic_store(&g_done[0], 0u, __ATOMIC_RELAXED,
                         __HIP_MEMORY_SCOPE_AGENT);
  }
}

// s2: GRU1 (WGs 0..63); gh0' for next step (64..127). Grid 128.
__global__ void k_s2(const float* __restrict__ b_ih1, const float* __restrict__ b_hh0) {
  const int wg = blockIdx.x, tid = threadIdx.x;
  const int lane = tid & 63, wv = tid >> 6;
  __shared__ __align__(16) float sh[1536];
  const int qa = (wv < 2) ? wv * 2 : wv + 2;
  const int qb = (wv < 2) ? wv * 2 + 1 : -1;
  const bool lo = (wg < 64);
  const int w16 = wg & 63;
  const ushort_t* SW = g_sw + (lo ? SB_IH1 : SB_HH0);
  { int g = qa >> 1, mu = qa & 1;
    put_tile(sh, qa, lane, gemm_plain(g_h0b, SW, g * 64 + w16, mu, lane)); }
  if (qb >= 0) { int g = qb >> 1, mu = qb & 1;
    put_tile(sh, qb, lane, gemm_plain(g_h0b, SW, g * 64 + w16, mu, lane)); }
  __syncthreads();
  const int jl = tid & 15, mr = tid >> 4, jg = w16 * 16 + jl;
  if (lo) {
    const float bir = b_ih1[jg], biz = b_ih1[1024 + jg], bin = b_ih1[2048 + jg];
#pragma unroll
    for (int mu = 0; mu < 2; ++mu) {
      const int b = mu * 16 + mr;
      float gr = sh[mu * 256 + tid]       + bir + g_gh1[b * 3072 + jg];
      float gz = sh[(2 + mu) * 256 + tid] + biz + g_gh1[b * 3072 + 1024 + jg];
      float gn = sh[(4 + mu) * 256 + tid] + bin;
      float r = sigm(gr), z = sigm(gz);
      float nn = tanhf(gn + r * g_gh1[b * 3072 + 2048 + jg]);
      float h = (1.f - z) * nn + z * g_h1f[b * 1024 + jg];
      g_h1f[b * 1024 + jg] = h; g_h1b[b * 1024 + jg] = f2b(h);
    }
  } else {
#pragma unroll
    for (int mu = 0; mu < 2; ++mu) {
      const int b = mu * 16 + mr;
#pragma unroll
      for (int g = 0; g < 3; ++g)
        g_gh0[b * 3072 + g * 1024 + jg] = sh[(g * 2 + mu) * 256 + tid] + b_hh0[g * 1024 + jg];
    }
  }
}

// ---------------------------------------------------------------------------
// s34: attention (WGs 0..255, fp8 + LDS decode table, ctx/den atomics, then
// done++); co = tanh([h1|ctx]@Wc^T+bc) (256..319, spin on done, ctx via sc);
// gh1' (320..383, spin-free). Grid 384.
// ---------------------------------------------------------------------------
__global__ void k_s34(const float* __restrict__ bc, const float* __restrict__ b_hh1) {
  __shared__ __align__(16) float sh[4160];
  __shared__ __align__(16) float tabf[256];
  const int wg = blockIdx.x, tid = threadIdx.x;
  const int lane = tid & 63, wv = tid >> 6;
  if (wg < 256) {
    {  // build fp8 e4m3 -> f32 decode table
      const unsigned v = (unsigned)tid;
      const unsigned e = (v >> 3) & 0xFu, m = v & 7u;
      union { unsigned u; float f; } c;
      if (e == 0u) c.f = (float)m * 0.001953125f;       // m * 2^-9
      else c.u = ((e + 120u) << 23) | (m << 20);
      c.u |= (v & 0x80u) << 24;
      tabf[v] = c.f;
    }
    const int b = wg >> 3, slot = wg & 7;
    const float* hp = g_h1f + b * 1024;
    float u0[8], u1[8];
    {
      float4v a0 = *(const float4v*)(hp + lane * 8);
      float4v a1 = *(const float4v*)(hp + lane * 8 + 4);
      float4v b0 = *(const float4v*)(hp + 512 + lane * 8);
      float4v b1 = *(const float4v*)(hp + 512 + lane * 8 + 4);
#pragma unroll
      for (int j = 0; j < 4; ++j) {
        u0[j] = a0[j]; u0[4 + j] = a1[j];
        u1[j] = b0[j]; u1[4 + j] = b1[j];
      }
    }
    __syncthreads();           // table ready
    float cx0[8] = {0.f, 0.f, 0.f, 0.f, 0.f, 0.f, 0.f, 0.f};
    float cx1[8] = {0.f, 0.f, 0.f, 0.f, 0.f, 0.f, 0.f, 0.f};
    float sw = 0.f;
    const size_t base = ((size_t)(b * 512 + slot * 64 + wv * 16)) * 1024 + lane * 8;
    for (int it = 0; it < 16; ++it) {
      const size_t off = base + (size_t)it * 1024;
      uint2v gE0 = *(const uint2v*)(g_en8 + off);
      uint2v gE1 = *(const uint2v*)(g_en8 + off + 512);
      uint2v eE0 = *(const uint2v*)(g_ec8 + off);
      uint2v eE1 = *(const uint2v*)(g_ec8 + off + 512);
      float ef0[8], ef1[8];
      float s = 0.f;
#pragma unroll
      for (int w = 0; w < 2; ++w)
#pragma unroll
        for (int j = 0; j < 4; ++j) {
          const int k = w * 4 + j;
          s += u0[k] * tabf[(gE0[w] >> (8 * j)) & 0xffu];
          s += u1[k] * tabf[(gE1[w] >> (8 * j)) & 0xffu];
          ef0[k] = tabf[(eE0[w] >> (8 * j)) & 0xffu];
          ef1[k] = tabf[(eE1[w] >> (8 * j)) & 0xffu];
        }
      for (int o = 1; o < 64; o <<= 1) s += __shfl_xor(s, o, 64);
      const float sc = fminf(fmaxf(s, -70.f), 70.f);  // identity in legit regime
      const float p = __expf(sc);
      sw += p;
#pragma unroll
      for (int j = 0; j < 8; ++j) { cx0[j] += p * ef0[j]; cx1[j] += p * ef1[j]; }
    }
#pragma unroll
    for (int j = 0; j < 8; ++j) {
      sh[wv * 1024 + lane * 8 + j]       = cx0[j];
      sh[wv * 1024 + 512 + lane * 8 + j] = cx1[j];
    }
    if (lane == 0) sh[4096 + wv] = sw;
    __syncthreads();
    float4v t4 = {0.f, 0.f, 0.f, 0.f};
#pragma unroll
    for (int v = 0; v < 4; ++v) t4 += *(const float4v*)&sh[v * 1024 + tid * 4];
    float* dst = g_ctxn + b * 1024 + tid * 4;
#pragma unroll
    for (int c = 0; c < 4; ++c) unsafeAtomicAdd(dst + c, t4[c]);
    if (tid == 0)
      unsafeAtomicAdd(&g_sden[b], sh[4096] + sh[4097] + sh[4098] + sh[4099]);
    __syncthreads();           // drains vmcnt: ctx/den atomics complete
    if (tid == 0)
      __hip_atomic_fetch_add(&g_done[0], 1u, __ATOMIC_RELAXED,
                             __HIP_MEMORY_SCOPE_AGENT);
  } else if (wg < 320) {
    const int w16 = wg - 256;
    if (tid == 0) {            // bounded spin: all 256 attn WGs done
      unsigned spins = 0;
      while (__hip_atomic_load(&g_done[0], __ATOMIC_RELAXED,
                               __HIP_MEMORY_SCOPE_AGENT) < 256u) {
        __builtin_amdgcn_s_sleep(2);
        if (++spins > (1u << 22)) break;   // proceed (wrong, not hung)
      }
    }
    __syncthreads();
    if (wv < 2)
      put_tile(sh, wv, lane, gemm_scE2(g_h1b, g_ctxn, g_sden, g_sw + SB_WC, w16, wv, lane));
    __syncthreads();
    const int jl = tid & 15, mr = tid >> 4;
    const float bcv = bc[w16 * 16 + jl];
#pragma unroll
    for (int mu = 0; mu < 2; ++mu) {
      const int b = mu * 16 + mr;
      const float v = tanhf(sh[mu * 256 + tid] + bcv);
      g_cof[b * 1024 + w16 * 16 + jl] = v;
      g_cob[b * 1024 + w16 * 16 + jl] = f2b(v);
    }
  } else {
    const int w16 = wg - 320;
    const int qa = (wv < 2) ? wv * 2 : wv + 2;
    const int qb = (wv < 2) ? wv * 2 + 1 : -1;
    { int g = qa >> 1, mu = qa & 1;
      put_tile(sh, qa, lane, gemm_plain(g_h1b, g_sw + SB_HH1, g * 64 + w16, mu, lane)); }
    if (qb >= 0) { int g = qb >> 1, mu = qb & 1;
      put_tile(sh, qb, lane, gemm_plain(g_h1b, g_sw + SB_HH1, g * 64 + w16, mu, lane)); }
    __syncthreads();
    const int jl = tid & 15, mr = tid >> 4, jg = w16 * 16 + jl;
#pragma unroll
    for (int mu = 0; mu < 2; ++mu) {
      const int b = mu * 16 + mr;
#pragma unroll
      for (int g = 0; g < 3; ++g)
        g_gh1[b * 3072 + g * 1024 + jg] = sh[(g * 2 + mu) * 256 + tid] + b_hh1[g * 1024 + jg];
    }
  }
}

extern "C" void kernel_launch(void* const* d_in, const int* in_sizes, int n_in,
                              void* d_out, int out_size, void* d_ws, size_t ws_size,
                              hipStream_t stream) {
  const float* ehid  = (const float*)d_in[0];
  const float* enc   = (const float*)d_in[1];
  const int*   lens  = (const int*)d_in[3];
  const float* W_attn= (const float*)d_in[4];
  const float* b_attn= (const float*)d_in[5];
  const float* W_ih0 = (const float*)d_in[6];
  const float* W_hh0 = (const float*)d_in[7];
  const float* b_ih0 = (const float*)d_in[8];
  const float* b_hh0 = (const float*)d_in[9];
  const float* W_ih1 = (const float*)d_in[10];
  const float* W_hh1 = (const float*)d_in[11];
  const float* b_ih1 = (const float*)d_in[12];
  const float* b_hh1 = (const float*)d_in[13];
  const float* Wc    = (const float*)d_in[14];
  const float* bc    = (const float*)d_in[15];
  const float* Wp    = (const float*)d_in[16];
  const float* bp    = (const float*)d_in[17];
  const float* Wg    = (const float*)d_in[18];
  const float* bg    = (const float*)d_in[19];
  float* out = (float*)d_out;

  k_wf    <<<1536, 256, 0, stream>>>(W_ih0, Wp);
  k_encb  <<<8192, 256, 0, stream>>>(enc);
  k_q8    <<<8192, 256, 0, stream>>>(enc);
  k_swz   <<<7744, 256, 0, stream>>>(W_ih1, W_hh0, W_hh1, W_attn, Wc, Wp);
  k_energy<<<512,  256, 0, stream>>>(b_attn);
  k_init  <<<318,  256, 0, stream>>>(ehid, lens, W_ih0, bp, b_ih0, out, out_size);
  k_pre   <<<128,  256, 0, stream>>>(b_hh0, b_hh1);
  for (int t = 0; t < TM; ++t) {
    k_s1 <<<81,  256, 0, stream>>>(t, b_ih0, bp, Wg, bg, lens, out, out_size);
    k_s2 <<<128, 256, 0, stream>>>(b_ih1, b_hh0);
    k_s34<<<384, 256, 0, stream>>>(bc, b_hh1);
  }
  k_s1<<<81, 256, 0, stream>>>(TM, b_ih0, bp, Wg, bg, lens, out, out_size);
}